// Round 1
// baseline (229.644 us; speedup 1.0000x reference)
//
#include <hip/hip_runtime.h>
#include <math.h>

#define HH 256
#define WW 256
#define NIMG 8          // B*C = 4*2
#define NF 32           // 8 images * 4 fields (p_fg, p_bg, t_fg, t_bg)
#define FLDSZ (HH * WW) // 65536
#define NELEM (NIMG * FLDSZ)
#define LARGE (1 << 27)
#define SENT 0xFFFFu

// ws layout:
// [0, 8)        double acc
// [8, 136)      int32 maxbuf[32]
// [256, 256+4MB)    u16 d1[NF][H][W]
// [256+4MB, +8MB)   f32 dist[NF][H][W]

// ---------------- pass 1: 1D DT along W (mask computed on the fly) ----------
__global__ __launch_bounds__(256) void hdt_pass1(
    const float* __restrict__ preds, const float* __restrict__ targets,
    unsigned short* __restrict__ d1)
{
    const int f   = blockIdx.x >> 8;   // field 0..31
    const int r   = blockIdx.x & 255;  // row
    const int img = f >> 2;
    const int k   = f & 3;             // 0:p_fg 1:p_bg 2:t_fg 3:t_bg
    const int i   = threadIdx.x;

    __shared__ int frow[WW];

    const float* src = (k < 2) ? preds : targets;
    const float  thr = (k < 2) ? 0.0f : 0.5f;   // sigmoid(x)>0.5 <=> x>0
    float v  = src[(size_t)(img * HH + r) * WW + i];
    bool  fg = v > thr;
    bool  m  = (k & 1) ? !fg : fg;
    frow[i]  = m ? LARGE : 0;
    __syncthreads();

    int best = 0x7fffffff;
#pragma unroll 8
    for (int j = 0; j < WW; ++j) {
        int d = i - j;
        best = min(best, frow[j] + d * d);
    }
    d1[(size_t)f * FLDSZ + r * WW + i] =
        (best >= LARGE) ? (unsigned short)SENT : (unsigned short)best;
}

// ---------------- pass 2: 1D DT along H + sqrt + per-field max --------------
__global__ __launch_bounds__(256) void hdt_pass2(
    const unsigned short* __restrict__ d1,
    float* __restrict__ dist, int* __restrict__ maxbuf)
{
    const int f = blockIdx.x >> 8;    // field
    const int i = blockIdx.x & 255;   // output row
    const int c = threadIdx.x;        // column

    const unsigned short* base = d1 + (size_t)f * FLDSZ + c;
    int best = 0x7fffffff;
#pragma unroll 8
    for (int j = 0; j < HH; ++j) {
        int v   = base[(size_t)j * WW];
        int val = (v == (int)SENT) ? LARGE : v;
        int d   = i - j;
        best = min(best, val + d * d);
    }

    float ds = (best >= LARGE) ? 1e6f : sqrtf((float)best);
    dist[(size_t)f * FLDSZ + i * WW + c] = ds;

    // block max-reduce of best -> atomicMax per field
    int bm = best;
#pragma unroll
    for (int off = 32; off > 0; off >>= 1)
        bm = max(bm, __shfl_down(bm, off));
    __shared__ int wmax[4];
    const int lane = threadIdx.x & 63, wid = threadIdx.x >> 6;
    if (lane == 0) wmax[wid] = bm;
    __syncthreads();
    if (threadIdx.x == 0) {
        int mm = max(max(wmax[0], wmax[1]), max(wmax[2], wmax[3]));
        atomicMax(maxbuf + f, mm);
    }
}

// ---------------- combine: loss terms + reduction ---------------------------
__device__ __forceinline__ float norm_from_max(int m)
{
    return (m >= LARGE) ? 1e6f : sqrtf((float)m);
}

__global__ __launch_bounds__(256) void hdt_combine(
    const float* __restrict__ preds, const float* __restrict__ targets,
    const float* __restrict__ dist, const int* __restrict__ maxbuf,
    double* __restrict__ acc)
{
    const int e   = blockIdx.x * 256 + threadIdx.x;  // < 524288
    const int img = e >> 16;
    const int pix = e & 65535;

    float x = preds[e];
    float t = targets[e];
    float p = 1.0f / (1.0f + expf(-x));
    float err = (p - t) * (p - t);

    const size_t b = (size_t)img * 4 * FLDSZ + pix;
    float dpf = dist[b];
    float dpb = dist[b + FLDSZ];
    float dtf = dist[b + 2 * FLDSZ];
    float dtb = dist[b + 3 * FLDSZ];

    int mpf = maxbuf[img * 4 + 0];
    int mpb = maxbuf[img * 4 + 1];
    int mtf = maxbuf[img * 4 + 2];
    int mtb = maxbuf[img * 4 + 3];

    float fieldp = 0.0f, fieldt = 0.0f;
    if (mpf > 0) {
        fieldp = dpf / fmaxf(norm_from_max(mpf), 1e-12f);
        if (mpb > 0) fieldp += dpb / fmaxf(norm_from_max(mpb), 1e-12f);
    }
    if (mtf > 0) {
        fieldt = dtf / fmaxf(norm_from_max(mtf), 1e-12f);
        if (mtb > 0) fieldt += dtb / fmaxf(norm_from_max(mtb), 1e-12f);
    }

    float term = err * (fieldp * fieldp + fieldt * fieldt);

    // block reduction
#pragma unroll
    for (int off = 32; off > 0; off >>= 1)
        term += __shfl_down(term, off);
    __shared__ float wsum[4];
    const int lane = threadIdx.x & 63, wid = threadIdx.x >> 6;
    if (lane == 0) wsum[wid] = term;
    __syncthreads();
    if (threadIdx.x == 0) {
        float bs = wsum[0] + wsum[1] + wsum[2] + wsum[3];
        atomicAdd(acc, (double)bs);
    }
}

__global__ void hdt_finalize(const double* __restrict__ acc, float* __restrict__ out)
{
    out[0] = (float)(acc[0] * (1.0 / (double)NELEM));
}

extern "C" void kernel_launch(void* const* d_in, const int* in_sizes, int n_in,
                              void* d_out, int out_size, void* d_ws, size_t ws_size,
                              hipStream_t stream)
{
    const float* preds   = (const float*)d_in[0];
    const float* targets = (const float*)d_in[1];
    float* out = (float*)d_out;

    char* ws = (char*)d_ws;
    double* acc  = (double*)ws;
    int* maxbuf  = (int*)(ws + 8);
    unsigned short* d1 = (unsigned short*)(ws + 256);
    float* dist = (float*)(ws + 256 + (size_t)NF * FLDSZ * 2);

    hipMemsetAsync(ws, 0, 256, stream);  // zero acc + maxbuf

    hdt_pass1<<<NF * HH, 256, 0, stream>>>(preds, targets, d1);
    hdt_pass2<<<NF * HH, 256, 0, stream>>>(d1, dist, maxbuf);
    hdt_combine<<<NELEM / 256, 256, 0, stream>>>(preds, targets, dist, maxbuf, acc);
    hdt_finalize<<<1, 1, 0, stream>>>(acc, out);
}

// Round 3
// 146.857 us; speedup vs baseline: 1.5637x; 1.5637x over previous
//
#include <hip/hip_runtime.h>
#include <math.h>

#define HH 256
#define WW 256
#define NIMG 8          // B*C = 4*2
#define NF 32           // 8 images * 4 fields (p_fg, p_bg, t_fg, t_bg)
#define FLDSZ (HH * WW) // 65536
#define NELEM (NIMG * FLDSZ)
#define LARGE (1 << 27)
#define SENT 0xFFFF
#define BIGD (1 << 20)

// ws layout:
// [0, 8)        double acc
// [8, 136)      int32 maxbuf[32]
// [256, 256+4MB)    u16 d1[NF][H][W]
// [256+4MB, +8MB)   f32 dist[NF][H][W]

// ---- pass 1: exact row DT via ballot bitmask nearest-set-bit ---------------
// One block per (img, row). Computes all 4 fields for that row.
__global__ __launch_bounds__(256) void hdt_pass1(
    const float* __restrict__ preds, const float* __restrict__ targets,
    unsigned short* __restrict__ d1)
{
    const int img = blockIdx.x >> 8;
    const int r   = blockIdx.x & 255;
    const int i   = threadIdx.x;
    const int lane = i & 63, wv = i >> 6;

    __shared__ unsigned long long bmask[2][4];  // [0]=preds fg bits, [1]=targets fg bits

    float pv = preds[((size_t)img * HH + r) * WW + i];
    float tv = targets[((size_t)img * HH + r) * WW + i];
    unsigned long long bp = __ballot(pv > 0.0f);   // sigmoid(x)>0.5 <=> x>0
    unsigned long long bt = __ballot(tv > 0.5f);
    if (lane == 0) { bmask[0][wv] = bp; bmask[1][wv] = bt; }
    __syncthreads();

#pragma unroll
    for (int k = 0; k < 4; ++k) {            // 0:p_fg 1:p_bg 2:t_fg 3:t_bg
        const int  which = k >> 1;
        const bool inv   = ((k & 1) == 0);   // fg field: sources are NON-fg pixels
        int bestd = BIGD;
#pragma unroll
        for (int w = 0; w < 4; ++w) {
            unsigned long long m = bmask[which][w];
            if (inv) m = ~m;
            if (!m) continue;
            const int base = w * 64;
            int d;
            if (base + 63 < i) {
                d = i - (base + 63 - __builtin_clzll(m));
            } else if (base > i) {
                d = base + __builtin_ctzll(m) - i;
            } else {
                const int t = i - base;
                unsigned long long lowm = (t == 63) ? m : (m & ((1ull << (t + 1)) - 1ull));
                unsigned long long him  = m >> t;
                int dl = lowm ? (t - (63 - __builtin_clzll(lowm))) : BIGD;
                int dr = him  ? __builtin_ctzll(him) : BIGD;
                d = min(dl, dr);
            }
            bestd = min(bestd, d);
        }
        unsigned short out = (bestd > 255) ? (unsigned short)SENT
                                           : (unsigned short)(bestd * bestd);
        d1[(size_t)(img * 4 + k) * FLDSZ + r * WW + i] = out;
    }
}

// ---- pass 2: column DT with adaptive outward scan + sqrt + per-field max ---
__global__ __launch_bounds__(256) void hdt_pass2(
    const unsigned short* __restrict__ d1,
    float* __restrict__ dist, int* __restrict__ maxbuf)
{
    const int f = blockIdx.x >> 8;    // field
    const int i = blockIdx.x & 255;   // output row
    const int c = threadIdx.x;        // column

    const unsigned short* base = d1 + (size_t)f * FLDSZ + c;

    int v0 = base[(size_t)i * WW];
    int best = (v0 == SENT) ? LARGE : v0;

    for (int r = 1; r < HH; ++r) {
        const int rr = r * r;
        if (__all(rr >= best)) break;   // no farther row can improve any lane
        const int jd = i - r, ju = i + r;
        if (jd >= 0) {
            int v = base[(size_t)jd * WW];
            v = (v == SENT) ? LARGE : v;
            best = min(best, v + rr);
        }
        if (ju < HH) {
            int v = base[(size_t)ju * WW];
            v = (v == SENT) ? LARGE : v;
            best = min(best, v + rr);
        }
    }

    float ds = (best >= LARGE) ? 1e6f : sqrtf((float)best);
    dist[(size_t)f * FLDSZ + i * WW + c] = ds;

    int bm = best;
#pragma unroll
    for (int off = 32; off > 0; off >>= 1)
        bm = max(bm, __shfl_down(bm, off));
    __shared__ int wmax[4];
    const int lane = threadIdx.x & 63, wid = threadIdx.x >> 6;
    if (lane == 0) wmax[wid] = bm;
    __syncthreads();
    if (threadIdx.x == 0) {
        int mm = max(max(wmax[0], wmax[1]), max(wmax[2], wmax[3]));
        atomicMax(maxbuf + f, mm);
    }
}

// ---- combine: loss terms + reduction (float4) ------------------------------
__device__ __forceinline__ float norm_from_max(int m)
{
    return (m >= LARGE) ? 1e6f : sqrtf((float)m);
}

__global__ __launch_bounds__(256) void hdt_combine(
    const float* __restrict__ preds, const float* __restrict__ targets,
    const float* __restrict__ dist, const int* __restrict__ maxbuf,
    double* __restrict__ acc)
{
    const int e4  = blockIdx.x * 256 + threadIdx.x;  // < 131072
    const int e   = e4 * 4;
    const int img = e >> 16;
    const int pix = e & 65535;

    float4 x = ((const float4*)preds)[e4];
    float4 t = ((const float4*)targets)[e4];

    const size_t b = ((size_t)img * 4 * FLDSZ + pix) >> 2;
    float4 dpf = ((const float4*)dist)[b];
    float4 dpb = ((const float4*)dist)[b + FLDSZ / 4];
    float4 dtf = ((const float4*)dist)[b + 2 * FLDSZ / 4];
    float4 dtb = ((const float4*)dist)[b + 3 * FLDSZ / 4];

    const int mpf = maxbuf[img * 4 + 0];
    const int mpb = maxbuf[img * 4 + 1];
    const int mtf = maxbuf[img * 4 + 2];
    const int mtb = maxbuf[img * 4 + 3];

    const float inv_pf = (mpf > 0) ? 1.0f / fmaxf(norm_from_max(mpf), 1e-12f) : 0.0f;
    const float inv_pb = (mpf > 0 && mpb > 0) ? 1.0f / fmaxf(norm_from_max(mpb), 1e-12f) : 0.0f;
    const float inv_tf = (mtf > 0) ? 1.0f / fmaxf(norm_from_max(mtf), 1e-12f) : 0.0f;
    const float inv_tb = (mtf > 0 && mtb > 0) ? 1.0f / fmaxf(norm_from_max(mtb), 1e-12f) : 0.0f;

    float term = 0.0f;
    {
        const float xs[4] = {x.x, x.y, x.z, x.w};
        const float ts[4] = {t.x, t.y, t.z, t.w};
        const float pf[4] = {dpf.x, dpf.y, dpf.z, dpf.w};
        const float pb[4] = {dpb.x, dpb.y, dpb.z, dpb.w};
        const float tf[4] = {dtf.x, dtf.y, dtf.z, dtf.w};
        const float tb[4] = {dtb.x, dtb.y, dtb.z, dtb.w};
#pragma unroll
        for (int q = 0; q < 4; ++q) {
            float p   = 1.0f / (1.0f + expf(-xs[q]));
            float err = (p - ts[q]) * (p - ts[q]);
            float fieldp = pf[q] * inv_pf + pb[q] * inv_pb;
            float fieldt = tf[q] * inv_tf + tb[q] * inv_tb;
            term += err * (fieldp * fieldp + fieldt * fieldt);
        }
    }

#pragma unroll
    for (int off = 32; off > 0; off >>= 1)
        term += __shfl_down(term, off);
    __shared__ float wsum[4];
    const int lane = threadIdx.x & 63, wid = threadIdx.x >> 6;
    if (lane == 0) wsum[wid] = term;
    __syncthreads();
    if (threadIdx.x == 0) {
        float bs = wsum[0] + wsum[1] + wsum[2] + wsum[3];
        atomicAdd(acc, (double)bs);
    }
}

__global__ void hdt_finalize(const double* __restrict__ acc, float* __restrict__ out)
{
    out[0] = (float)(acc[0] * (1.0 / (double)NELEM));
}

extern "C" void kernel_launch(void* const* d_in, const int* in_sizes, int n_in,
                              void* d_out, int out_size, void* d_ws, size_t ws_size,
                              hipStream_t stream)
{
    const float* preds   = (const float*)d_in[0];
    const float* targets = (const float*)d_in[1];
    float* out = (float*)d_out;

    char* ws = (char*)d_ws;
    double* acc  = (double*)ws;
    int* maxbuf  = (int*)(ws + 8);
    unsigned short* d1 = (unsigned short*)(ws + 256);
    float* dist = (float*)(ws + 256 + (size_t)NF * FLDSZ * 2);

    hipMemsetAsync(ws, 0, 256, stream);  // zero acc + maxbuf

    hdt_pass1<<<NIMG * HH, 256, 0, stream>>>(preds, targets, d1);
    hdt_pass2<<<NF * HH, 256, 0, stream>>>(d1, dist, maxbuf);
    hdt_combine<<<NELEM / 4 / 256, 256, 0, stream>>>(preds, targets, dist, maxbuf, acc);
    hdt_finalize<<<1, 1, 0, stream>>>(acc, out);
}

// Round 4
// 89.134 us; speedup vs baseline: 2.5764x; 1.6476x over previous
//
#include <hip/hip_runtime.h>
#include <math.h>

#define HH 256
#define WW 256
#define NIMG 8          // B*C = 4*2
#define NF 32           // 8 images * 4 fields (p_fg, p_bg, t_fg, t_bg)
#define FLDSZ (HH * WW) // 65536
#define NELEM (NIMG * FLDSZ)
#define LARGE (1 << 27)
#define SENT 0xFFFF
#define BIGD (1 << 20)

// ws layout:
// [0, 4MB)          u16 d1[NF][H][W]   (row-pass d^2, 0xFFFF = empty-row sentinel)
// [4MB, 12MB)       f32 dist[NF][H][W]
// [12MB, +1KB)      int blockmax[NF][8]
// [+1KB, +2KB)      f32 partial[512]
#define D1_OFF   0
#define DIST_OFF (4u * 1024 * 1024)
#define BMAX_OFF (12u * 1024 * 1024)
#define PART_OFF (BMAX_OFF + 1024)

__device__ __forceinline__ int nearest_bit_dist(const unsigned long long m[4], int i)
{
    int bestd = BIGD;
#pragma unroll
    for (int w = 0; w < 4; ++w) {
        unsigned long long mm = m[w];
        if (!mm) continue;                  // wave-uniform (mask words are uniform)
        const int base = w * 64;
        int d;
        if (base + 63 < i) {
            d = i - (base + 63 - __builtin_clzll(mm));
        } else if (base > i) {
            d = base + __builtin_ctzll(mm) - i;
        } else {
            const int t = i - base;
            unsigned long long lowm = (t == 63) ? mm : (mm & ((1ull << (t + 1)) - 1ull));
            unsigned long long him  = mm >> t;
            int dl = lowm ? (t - (63 - __builtin_clzll(lowm))) : BIGD;
            int dr = him  ? __builtin_ctzll(him) : BIGD;
            d = min(dl, dr);
        }
        bestd = min(bestd, d);
    }
    return bestd;
}

// ---- kernel 1: row DT for all 4 fields, 8 rows per block -------------------
__global__ __launch_bounds__(256) void k_rowdt(
    const float* __restrict__ preds, const float* __restrict__ targets,
    unsigned short* __restrict__ d1)
{
    const int img = blockIdx.x >> 5;   // 8 images
    const int rg  = blockIdx.x & 31;   // 32 groups of 8 rows
    const int i   = threadIdx.x;       // column
    const int lane = i & 63, wv = i >> 6;

    __shared__ unsigned long long pm[8][4], tm[8][4];

    const size_t ibase = ((size_t)img * HH + rg * 8) * WW;
#pragma unroll
    for (int r8 = 0; r8 < 8; ++r8) {
        float pv = preds[ibase + r8 * WW + i];
        float tv = targets[ibase + r8 * WW + i];
        unsigned long long bp = __ballot(pv > 0.0f);   // sigmoid(x)>0.5 <=> x>0
        unsigned long long bt = __ballot(tv > 0.5f);
        if (lane == 0) { pm[r8][wv] = bp; tm[r8][wv] = bt; }
    }
    __syncthreads();

#pragma unroll
    for (int k = 0; k < 4; ++k) {        // 0:p_fg 1:p_bg 2:t_fg 3:t_bg
        const bool usep = (k < 2);
        const bool inv  = ((k & 1) == 0);  // fg field: sources = non-mask pixels
#pragma unroll
        for (int r8 = 0; r8 < 8; ++r8) {
            unsigned long long mw[4];
#pragma unroll
            for (int w = 0; w < 4; ++w) {
                unsigned long long m = usep ? pm[r8][w] : tm[r8][w];
                mw[w] = inv ? ~m : m;
            }
            int bestd = nearest_bit_dist(mw, i);
            unsigned short out = (bestd > 255) ? (unsigned short)SENT
                                               : (unsigned short)(bestd * bestd);
            d1[(size_t)(img * 4 + k) * FLDSZ + (rg * 8 + r8) * WW + i] = out;
        }
    }
}

// ---- kernel 2: column DT from LDS-staged field + per-block max -------------
__global__ __launch_bounds__(512) void k_coldt(
    const unsigned short* __restrict__ d1,
    float* __restrict__ dist, int* __restrict__ blockmax)
{
    const int f  = blockIdx.x >> 3;   // field
    const int rg = blockIdx.x & 7;    // 32-row output group

    __shared__ unsigned short s[FLDSZ];   // 128 KiB: whole field
    __shared__ int wmax[8];

    // stage whole field: 131072 B = 8192 uint4
    const uint4* src = (const uint4*)(d1 + (size_t)f * FLDSZ);
    uint4* dst = (uint4*)s;
    for (int it = threadIdx.x; it < FLDSZ * 2 / 16; it += 512) dst[it] = src[it];
    __syncthreads();

    const int c    = threadIdx.x & 255;   // column
    const int half = threadIdx.x >> 8;    // 0/1 (row parity within group)

    int blkmax = 0;
    for (int oi = 0; oi < 16; ++oi) {
        const int i = rg * 32 + half + oi * 2;   // output row
        int v0 = s[i * WW + c];
        int best = (v0 == SENT) ? LARGE : v0;
        for (int r = 1; r < HH; ++r) {
            const int rr = r * r;
            if (__all(rr >= best)) break;   // wave covers 64 cols of one row
            const int jd = i - r, ju = i + r;
            if (jd >= 0) {
                int v = s[jd * WW + c];
                best = min(best, ((v == SENT) ? LARGE : v) + rr);
            }
            if (ju < HH) {
                int v = s[ju * WW + c];
                best = min(best, ((v == SENT) ? LARGE : v) + rr);
            }
        }
        dist[(size_t)f * FLDSZ + i * WW + c] = (best >= LARGE) ? 1e6f : sqrtf((float)best);
        blkmax = max(blkmax, best);
    }

#pragma unroll
    for (int off = 32; off > 0; off >>= 1)
        blkmax = max(blkmax, __shfl_down(blkmax, off));
    if ((threadIdx.x & 63) == 0) wmax[threadIdx.x >> 6] = blkmax;
    __syncthreads();
    if (threadIdx.x == 0) {
        int m = wmax[0];
#pragma unroll
        for (int q = 1; q < 8; ++q) m = max(m, wmax[q]);
        blockmax[f * 8 + rg] = m;
    }
}

// ---- kernel 3: loss terms + per-block partial sums -------------------------
__device__ __forceinline__ float norm_from_max(int m)
{
    return (m >= LARGE) ? 1e6f : sqrtf((float)m);
}

__global__ __launch_bounds__(256) void k_combine(
    const float* __restrict__ preds, const float* __restrict__ targets,
    const float* __restrict__ dist, const int* __restrict__ blockmax,
    float* __restrict__ partial)
{
    const int img  = blockIdx.x >> 6;                      // 64 blocks per image
    const int pix4 = (blockIdx.x & 63) * 256 + threadIdx.x; // float4 index in image
    const int e4   = img * (FLDSZ / 4) + pix4;             // global float4 index

    int mpf = 0, mpb = 0, mtf = 0, mtb = 0;
#pragma unroll
    for (int q = 0; q < 8; ++q) {
        mpf = max(mpf, blockmax[(img * 4 + 0) * 8 + q]);
        mpb = max(mpb, blockmax[(img * 4 + 1) * 8 + q]);
        mtf = max(mtf, blockmax[(img * 4 + 2) * 8 + q]);
        mtb = max(mtb, blockmax[(img * 4 + 3) * 8 + q]);
    }

    float4 x = ((const float4*)preds)[e4];
    float4 t = ((const float4*)targets)[e4];

    const size_t b = (size_t)img * 4 * (FLDSZ / 4) + pix4;
    float4 dpf = ((const float4*)dist)[b];
    float4 dpb = ((const float4*)dist)[b + FLDSZ / 4];
    float4 dtf = ((const float4*)dist)[b + 2 * (FLDSZ / 4)];
    float4 dtb = ((const float4*)dist)[b + 3 * (FLDSZ / 4)];

    const float inv_pf = (mpf > 0) ? 1.0f / fmaxf(norm_from_max(mpf), 1e-12f) : 0.0f;
    const float inv_pb = (mpf > 0 && mpb > 0) ? 1.0f / fmaxf(norm_from_max(mpb), 1e-12f) : 0.0f;
    const float inv_tf = (mtf > 0) ? 1.0f / fmaxf(norm_from_max(mtf), 1e-12f) : 0.0f;
    const float inv_tb = (mtf > 0 && mtb > 0) ? 1.0f / fmaxf(norm_from_max(mtb), 1e-12f) : 0.0f;

    float term = 0.0f;
    {
        const float xs[4] = {x.x, x.y, x.z, x.w};
        const float ts[4] = {t.x, t.y, t.z, t.w};
        const float pf[4] = {dpf.x, dpf.y, dpf.z, dpf.w};
        const float pb[4] = {dpb.x, dpb.y, dpb.z, dpb.w};
        const float tf[4] = {dtf.x, dtf.y, dtf.z, dtf.w};
        const float tb[4] = {dtb.x, dtb.y, dtb.z, dtb.w};
#pragma unroll
        for (int q = 0; q < 4; ++q) {
            float p   = 1.0f / (1.0f + expf(-xs[q]));
            float err = (p - ts[q]) * (p - ts[q]);
            float fieldp = pf[q] * inv_pf + pb[q] * inv_pb;
            float fieldt = tf[q] * inv_tf + tb[q] * inv_tb;
            term += err * (fieldp * fieldp + fieldt * fieldt);
        }
    }

#pragma unroll
    for (int off = 32; off > 0; off >>= 1)
        term += __shfl_down(term, off);
    __shared__ float wsum[4];
    const int lane = threadIdx.x & 63, wid = threadIdx.x >> 6;
    if (lane == 0) wsum[wid] = term;
    __syncthreads();
    if (threadIdx.x == 0)
        partial[blockIdx.x] = wsum[0] + wsum[1] + wsum[2] + wsum[3];
}

// ---- kernel 4: final reduce of 512 partials --------------------------------
__global__ __launch_bounds__(256) void k_final(
    const float* __restrict__ partial, float* __restrict__ out)
{
    double v = (double)partial[threadIdx.x] + (double)partial[threadIdx.x + 256];
#pragma unroll
    for (int off = 32; off > 0; off >>= 1)
        v += __shfl_down(v, off);
    __shared__ double w[4];
    if ((threadIdx.x & 63) == 0) w[threadIdx.x >> 6] = v;
    __syncthreads();
    if (threadIdx.x == 0)
        out[0] = (float)((w[0] + w[1] + w[2] + w[3]) * (1.0 / (double)NELEM));
}

extern "C" void kernel_launch(void* const* d_in, const int* in_sizes, int n_in,
                              void* d_out, int out_size, void* d_ws, size_t ws_size,
                              hipStream_t stream)
{
    const float* preds   = (const float*)d_in[0];
    const float* targets = (const float*)d_in[1];
    float* out = (float*)d_out;

    char* ws = (char*)d_ws;
    unsigned short* d1 = (unsigned short*)(ws + D1_OFF);
    float* dist        = (float*)(ws + DIST_OFF);
    int* blockmax      = (int*)(ws + BMAX_OFF);
    float* partial     = (float*)(ws + PART_OFF);

    k_rowdt  <<<NIMG * 32, 256, 0, stream>>>(preds, targets, d1);
    k_coldt  <<<NF * 8,    512, 0, stream>>>(d1, dist, blockmax);
    k_combine<<<512,       256, 0, stream>>>(preds, targets, dist, blockmax, partial);
    k_final  <<<1,         256, 0, stream>>>(partial, out);
}

// Round 5
// 75.091 us; speedup vs baseline: 3.0582x; 1.1870x over previous
//
#include <hip/hip_runtime.h>
#include <math.h>

#define HH 256
#define WW 256
#define NIMG 8            // B*C
#define NF 32             // 8 images * 4 fields
#define FLDSZ (HH * WW)
#define NELEM (NIMG * FLDSZ)
#define LARGE (1 << 27)   // sentinel d^2 when a field has no source pixels at all
#define BIGD (1 << 20)
#define BIGC (1 << 26)    // capped row-dist^2 marker (window miss / row out of range)

// ws layout (all regions fully written before read; no memset needed):
// [0,      64KB)   u64 bmP[8][256][4]   preds fg bitmap
// [64KB,  128KB)   u64 bmT[8][256][4]   targets fg bitmap
// [128KB, 132KB)   f64 Apart[512]
// [132KB, 134KB)   i32 Mpart[512]
#define BMP_OFF 0
#define BMT_OFF (64u * 1024)
#define APA_OFF (128u * 1024)
#define MPA_OFF (132u * 1024)

// ---- K0: per-row 256-bit fg masks for preds and targets --------------------
__global__ __launch_bounds__(256) void k_bitmap(
    const float* __restrict__ preds, const float* __restrict__ targets,
    unsigned long long* __restrict__ bmP, unsigned long long* __restrict__ bmT)
{
    const int img = blockIdx.x >> 5;   // 8 images
    const int rg  = blockIdx.x & 31;   // 8-row group
    const int c   = threadIdx.x;
    const int lane = c & 63, wv = c >> 6;

    const size_t ibase = ((size_t)img * HH + rg * 8) * WW;
#pragma unroll
    for (int r8 = 0; r8 < 8; ++r8) {
        float pv = preds[ibase + r8 * WW + c];
        float tv = targets[ibase + r8 * WW + c];
        unsigned long long bp = __ballot(pv > 0.0f);   // sigmoid(x)>0.5 <=> x>0
        unsigned long long bt = __ballot(tv > 0.5f);
        if (lane == 0) {
            const int row = rg * 8 + r8;
            bmP[((size_t)img * HH + row) * 4 + wv] = bp;
            bmT[((size_t)img * HH + row) * 4 + wv] = bt;
        }
    }
}

// ---- row-distance helpers (sources = set bits in staged bitmap) ------------
// Windowed: exact if nearest source in row j is within ~63 cols, else BIGC.
__device__ __forceinline__ int win_rowd2(const unsigned long long* __restrict__ sbm,
                                         int j, int wq, int sh)
{
    unsigned long long cur = sbm[j * 4 + wq];
    unsigned long long lw  = (wq > 0) ? sbm[j * 4 + wq - 1] : 0ull;
    unsigned long long rw  = (wq < 3) ? sbm[j * 4 + wq + 1] : 0ull;
    unsigned long long A = cur >> sh;              // bit k = global col c+k
    if (sh) A |= rw << (64 - sh);
    int dR = A ? __builtin_ctzll(A) : 1000;
    unsigned long long L = (sh == 63) ? cur : (cur & ((1ull << (sh + 1)) - 1ull));
    int dL;
    if (L)       dL = sh - (63 - __builtin_clzll(L));
    else if (lw) dL = sh + 1 + __builtin_clzll(lw);
    else         dL = 1000;
    int d = min(dR, dL);
    return (d <= 255) ? d * d : BIGC;
}

// Full 4-word exact nearest-bit distance (lattice dist, BIGD if empty row).
__device__ __forceinline__ int full_rowd(const unsigned long long* __restrict__ sbm,
                                         int j, int c)
{
    int bestd = BIGD;
#pragma unroll
    for (int w = 0; w < 4; ++w) {
        unsigned long long mm = sbm[j * 4 + w];   // wave-uniform word
        if (!mm) continue;
        const int base = w * 64;
        int d;
        if (base + 63 < c) {
            d = c - (base + 63 - __builtin_clzll(mm));
        } else if (base > c) {
            d = base + __builtin_ctzll(mm) - c;
        } else {
            const int t = c - base;
            unsigned long long lowm = (t == 63) ? mm : (mm & ((1ull << (t + 1)) - 1ull));
            unsigned long long him  = mm >> t;
            int dl = lowm ? (t - (63 - __builtin_clzll(lowm))) : BIGD;
            int dr = him  ? __builtin_ctzll(him) : BIGD;
            d = min(dl, dr);
        }
        bestd = min(bestd, d);
    }
    return bestd;
}

// ---- K1: fused exact 2D EDT^2 + loss accumulation per field ----------------
// block = (field, 16-row group). LDS: inverted-as-needed bitmap (8 KB).
__global__ __launch_bounds__(256) void k_dtloss(
    const float* __restrict__ preds, const float* __restrict__ targets,
    const unsigned long long* __restrict__ bmP,
    const unsigned long long* __restrict__ bmT,
    double* __restrict__ Apart, int* __restrict__ Mpart)
{
    const int f   = blockIdx.x >> 4;    // field 0..31
    const int rg  = blockIdx.x & 15;    // 16-row group
    const int img = f >> 2;
    const int k   = f & 3;              // 0:p_fg 1:p_bg 2:t_fg 3:t_bg
    const int c   = threadIdx.x;
    const int wq  = c >> 6, sh = c & 63;

    __shared__ unsigned long long sbm[HH * 4];   // sources = set bits

    const unsigned long long* g = (k < 2) ? (bmP + (size_t)img * HH * 4)
                                          : (bmT + (size_t)img * HH * 4);
    const bool inv = ((k & 1) == 0);    // fg field: sources are NON-mask pixels
#pragma unroll
    for (int q = 0; q < 4; ++q) {
        unsigned long long w = g[q * 256 + c];
        sbm[q * 256 + c] = inv ? ~w : w;
    }
    __syncthreads();

    const int i0 = rg * 16;
    int rw9[9];
#pragma unroll
    for (int q = 0; q < 9; ++q) {
        const int j = i0 - 4 + q;
        rw9[q] = ((unsigned)j < HH) ? win_rowd2(sbm, j, wq, sh) : BIGC;
    }

    double accA = 0.0;
    int mx = 0;

    for (int ii = 0; ii < 16; ++ii) {
        const int i = i0 + ii;

        int best = rw9[4];
        best = min(best, min(rw9[3], rw9[5]) + 1);
        best = min(best, min(rw9[2], rw9[6]) + 4);
        best = min(best, min(rw9[1], rw9[7]) + 9);
        best = min(best, min(rw9[0], rw9[8]) + 16);

        if (__any(best > 16)) {
            // exact fallback (rare): adaptive outward scan with full row dist
            int d0 = full_rowd(sbm, i, c);
            int eb = (d0 <= 255) ? d0 * d0 : LARGE;
            for (int r = 1; r < HH; ++r) {
                if (__all(r * r >= eb)) break;
                const int jd = i - r, ju = i + r;
                if (jd >= 0) {
                    int d = full_rowd(sbm, jd, c);
                    if (d <= 255) eb = min(eb, d * d + r * r);
                }
                if (ju < HH) {
                    int d = full_rowd(sbm, ju, c);
                    if (d <= 255) eb = min(eb, d * d + r * r);
                }
            }
            best = eb;
        }

        // fused loss term: err(pixel) * d^2
        const size_t idx = ((size_t)img * HH + i) * WW + c;
        float x = preds[idx];
        float t = targets[idx];
        float p = 1.0f / (1.0f + expf(-x));
        float err = (p - t) * (p - t);
        accA += (double)err * (double)best;
        mx = max(mx, best);

        // shift window, fetch row i+5
#pragma unroll
        for (int q = 0; q < 8; ++q) rw9[q] = rw9[q + 1];
        const int jn = i + 5;
        rw9[8] = ((unsigned)jn < HH) ? win_rowd2(sbm, jn, wq, sh) : BIGC;
    }

    // block reduction (4 waves)
#pragma unroll
    for (int off = 32; off > 0; off >>= 1) {
        accA += __shfl_down(accA, off);
        mx = max(mx, __shfl_down(mx, off));
    }
    __shared__ double wA[4];
    __shared__ int    wM[4];
    const int lane = threadIdx.x & 63, wid = threadIdx.x >> 6;
    if (lane == 0) { wA[wid] = accA; wM[wid] = mx; }
    __syncthreads();
    if (threadIdx.x == 0) {
        double a = wA[0] + wA[1] + wA[2] + wA[3];
        int m = max(max(wM[0], wM[1]), max(wM[2], wM[3]));
        Apart[blockIdx.x] = a;
        Mpart[blockIdx.x] = m;
    }
}

// ---- K2: final reduce + gating + normalize ---------------------------------
__global__ __launch_bounds__(512) void k_final2(
    const double* __restrict__ Apart, const int* __restrict__ Mpart,
    float* __restrict__ out)
{
    const int t = threadIdx.x;          // 512 = 32 fields * 16 parts
    double v = Apart[t];
    int m = Mpart[t];
#pragma unroll
    for (int off = 8; off > 0; off >>= 1) {    // segments of 16 (wave-aligned)
        v += __shfl_down(v, off);
        m = max(m, __shfl_down(m, off));
    }
    __shared__ double sA[NF];
    __shared__ int    sM[NF];
    if ((t & 15) == 0) { sA[t >> 4] = v; sM[t >> 4] = m; }
    __syncthreads();
    if (t == 0) {
        double loss = 0.0;
        for (int img = 0; img < NIMG; ++img) {
            const double a0 = sA[img * 4 + 0], a1 = sA[img * 4 + 1];
            const double a2 = sA[img * 4 + 2], a3 = sA[img * 4 + 3];
            const int m0 = sM[img * 4 + 0], m1 = sM[img * 4 + 1];
            const int m2 = sM[img * 4 + 2], m3 = sM[img * 4 + 3];
            if (m0 > 0) { loss += a0 / (double)m0; if (m1 > 0) loss += a1 / (double)m1; }
            if (m2 > 0) { loss += a2 / (double)m2; if (m3 > 0) loss += a3 / (double)m3; }
        }
        out[0] = (float)(loss / (double)NELEM);
    }
}

extern "C" void kernel_launch(void* const* d_in, const int* in_sizes, int n_in,
                              void* d_out, int out_size, void* d_ws, size_t ws_size,
                              hipStream_t stream)
{
    const float* preds   = (const float*)d_in[0];
    const float* targets = (const float*)d_in[1];
    float* out = (float*)d_out;

    char* ws = (char*)d_ws;
    unsigned long long* bmP = (unsigned long long*)(ws + BMP_OFF);
    unsigned long long* bmT = (unsigned long long*)(ws + BMT_OFF);
    double* Apart           = (double*)(ws + APA_OFF);
    int*    Mpart           = (int*)(ws + MPA_OFF);

    k_bitmap<<<NIMG * 32, 256, 0, stream>>>(preds, targets, bmP, bmT);
    k_dtloss<<<NF * 16,   256, 0, stream>>>(preds, targets, bmP, bmT, Apart, Mpart);
    k_final2<<<1,         512, 0, stream>>>(Apart, Mpart, out);
}